// Round 5
// baseline (293.577 us; speedup 1.0000x reference)
//
#include <hip/hip_runtime.h>
#include <hip/hip_bf16.h>
#include <stdint.h>

#define B_    16
#define C_    320
#define S_    4096
#define G_    32
#define LC    77
#define CTX   768
#define HEADS 8
#define HD    40

typedef __bf16 bf16x8_t __attribute__((ext_vector_type(8)));
typedef float  f32x4_t  __attribute__((ext_vector_type(4)));

__device__ __forceinline__ unsigned short f2bf(float f) {
    union { float f; unsigned int u; } v; v.f = f;
    unsigned int r = v.u + 0x7fffu + ((v.u >> 16) & 1u);
    return (unsigned short)(r >> 16);
}
__device__ __forceinline__ float bf2f(unsigned short h) {
    union { unsigned int u; float f; } v; v.u = ((unsigned int)h) << 16;
    return v.f;
}

// ---------------------------------------------------------------- GN stats
__global__ __launch_bounds__(256) void gn_stats(const float* __restrict__ x,
                                                float2* __restrict__ mr) {
    int bg = blockIdx.x;
    const float4* p = (const float4*)(x + (size_t)bg * 40960);
    float s = 0.f, s2 = 0.f;
    for (int i = threadIdx.x; i < 10240; i += 256) {
        float4 v = p[i];
        s  += v.x + v.y + v.z + v.w;
        s2 += v.x * v.x + v.y * v.y + v.z * v.z + v.w * v.w;
    }
    for (int o = 32; o; o >>= 1) {
        s  += __shfl_down(s, o);
        s2 += __shfl_down(s2, o);
    }
    __shared__ float2 red[4];
    int lane = threadIdx.x & 63, wid = threadIdx.x >> 6;
    if (lane == 0) red[wid] = make_float2(s, s2);
    __syncthreads();
    if (threadIdx.x == 0) {
        float a = 0.f, c = 0.f;
        for (int i = 0; i < 4; i++) { a += red[i].x; c += red[i].y; }
        float mean = a / 40960.f;
        float var  = c / 40960.f - mean * mean;
        mr[bg] = make_float2(mean, rsqrtf(var + 1e-5f));
    }
}

// ---------------------------------------------------------------- weight cast
__global__ __launch_bounds__(256) void castw(const float* __restrict__ s,
                                             unsigned short* __restrict__ d) {
    int i = blockIdx.x * 256 + threadIdx.x;
    float4 v = ((const float4*)s)[i];
    ushort4 o;
    o.x = f2bf(v.x); o.y = f2bf(v.y); o.z = f2bf(v.z); o.w = f2bf(v.w);
    ((ushort4*)d)[i] = o;
}

// ---------------------------------------------------------------- normalize + transpose
__global__ __launch_bounds__(256) void norm_tr(const float* __restrict__ x,
                                               const float2* __restrict__ mr,
                                               const float* __restrict__ gns,
                                               const float* __restrict__ gnb,
                                               unsigned short* __restrict__ tok) {
    int s0 = blockIdx.x * 32, c0 = blockIdx.y * 32, b = blockIdx.z;
    __shared__ unsigned short t[32][33];
    int tx = threadIdx.x & 31, ty = threadIdx.x >> 5;
    #pragma unroll
    for (int i = 0; i < 4; i++) {
        int cl = i * 8 + ty;
        int c = c0 + cl;
        float2 m = mr[b * 32 + c / 10];
        float v = x[((size_t)(b * 320 + c)) * 4096 + s0 + tx];
        v = (v - m.x) * m.y * gns[c] + gnb[c];
        t[cl][tx] = f2bf(v);
    }
    __syncthreads();
    #pragma unroll
    for (int i = 0; i < 4; i++) {
        int sl = i * 8 + ty;
        tok[((size_t)b * 4096 + s0 + sl) * 320 + c0 + tx] = t[tx][sl];
    }
}

// ---------------------------------------------------------------- U kernel
__global__ __launch_bounds__(256) void ukern(const float* __restrict__ Wk,
                                             const float* __restrict__ Wq,
                                             unsigned short* __restrict__ Ut) {
    int c = blockIdx.x, h = blockIdx.y;
    int t = threadIdx.x;
    float a0 = 0.f, a1 = 0.f, a2 = 0.f;
    for (int d = 0; d < HD; d++) {
        float wq = Wq[(size_t)(h * HD + d) * 320 + c];
        const float* wkr = Wk + (size_t)(h * HD + d) * CTX;
        a0 += wq * wkr[t];
        a1 += wq * wkr[t + 256];
        a2 += wq * wkr[t + 512];
    }
    unsigned short* o = Ut + ((size_t)h * 320 + c) * CTX;
    o[t]       = f2bf(a0);
    o[t + 256] = f2bf(a1);
    o[t + 512] = f2bf(a2);
}

// ---------------------------------------------------------------- fused K/V/M projection GEMM
__global__ __launch_bounds__(256) void kvM_gemm(const float* __restrict__ ctx,
                                                const float* __restrict__ Wv,
                                                const unsigned short* __restrict__ Ut,
                                                unsigned short* __restrict__ vout,
                                                unsigned short* __restrict__ Mout) {
    __shared__ unsigned short la[64][32], lb[64][32];
    int bm = blockIdx.x, bn = blockIdx.y;
    int tid = threadIdx.x, lane = tid & 63, wid = tid >> 6;
    int wm = wid >> 1, wn = wid & 1;
    int lr = tid >> 2, lc = (tid & 3) * 8;
    int fr = lane & 15, kk = (lane >> 4) * 8;

    int arow = bm * 64 + lr; if (arow > 1231) arow = 1231;
    const float* ap = ctx + (size_t)arow * CTX;
    bool isV = (bn < 5);
    const float* wp = isV ? (Wv + (size_t)(bn * 64 + lr) * CTX) : nullptr;
    const unsigned short* up = isV ? nullptr
        : (Ut + ((size_t)((bn - 5) / 5) * 320 + (size_t)((bn - 5) % 5) * 64 + lr) * CTX);

    f32x4_t acc[2][2] = {};
    for (int k0 = 0; k0 < CTX; k0 += 32) {
        float4 a4 = *(const float4*)&ap[k0 + lc];
        float4 a5 = *(const float4*)&ap[k0 + lc + 4];
        ushort4 pa0 = { f2bf(a4.x), f2bf(a4.y), f2bf(a4.z), f2bf(a4.w) };
        ushort4 pa1 = { f2bf(a5.x), f2bf(a5.y), f2bf(a5.z), f2bf(a5.w) };
        *(ushort4*)&la[lr][lc]     = pa0;
        *(ushort4*)&la[lr][lc + 4] = pa1;
        if (isV) {
            float4 w4 = *(const float4*)&wp[k0 + lc];
            float4 w5 = *(const float4*)&wp[k0 + lc + 4];
            ushort4 pw0 = { f2bf(w4.x), f2bf(w4.y), f2bf(w4.z), f2bf(w4.w) };
            ushort4 pw1 = { f2bf(w5.x), f2bf(w5.y), f2bf(w5.z), f2bf(w5.w) };
            *(ushort4*)&lb[lr][lc]     = pw0;
            *(ushort4*)&lb[lr][lc + 4] = pw1;
        } else {
            *(uint4*)&lb[lr][lc] = *(const uint4*)&up[k0 + lc];
        }
        __syncthreads();
        bf16x8_t a0 = *(const bf16x8_t*)&la[wm * 32 + fr][kk];
        bf16x8_t a1 = *(const bf16x8_t*)&la[wm * 32 + 16 + fr][kk];
        bf16x8_t b0 = *(const bf16x8_t*)&lb[wn * 32 + fr][kk];
        bf16x8_t b1 = *(const bf16x8_t*)&lb[wn * 32 + 16 + fr][kk];
        acc[0][0] = __builtin_amdgcn_mfma_f32_16x16x32_bf16(a0, b0, acc[0][0], 0, 0, 0);
        acc[0][1] = __builtin_amdgcn_mfma_f32_16x16x32_bf16(a0, b1, acc[0][1], 0, 0, 0);
        acc[1][0] = __builtin_amdgcn_mfma_f32_16x16x32_bf16(a1, b0, acc[1][0], 0, 0, 0);
        acc[1][1] = __builtin_amdgcn_mfma_f32_16x16x32_bf16(a1, b1, acc[1][1], 0, 0, 0);
        __syncthreads();
    }
    int rg = (lane >> 4) * 4;
    #pragma unroll
    for (int mf = 0; mf < 2; mf++)
        #pragma unroll
        for (int nf = 0; nf < 2; nf++)
            #pragma unroll
            for (int r = 0; r < 4; r++) {
                int row = bm * 64 + wm * 32 + mf * 16 + rg + r;
                if (row < 1232) {
                    int coloff = wn * 32 + nf * 16 + fr;
                    unsigned short val = f2bf(acc[mf][nf][r]);
                    if (isV) {
                        vout[(size_t)row * 320 + bn * 64 + coloff] = val;
                    } else {
                        int bb = row / 77, kv = row - bb * 77;
                        int h = (bn - 5) / 5;
                        int c = ((bn - 5) % 5) * 64 + coloff;
                        Mout[(((size_t)bb * 8 + h) * 77 + kv) * 320 + c] = val;
                    }
                }
            }
}

// ---------------------------------------------------------------- fused attention v3
// block = (qtile 128 rows, b); loops all 8 heads. tok A-fragments in REGISTERS
// (loaded once). Per-head M_h/V_h double-buffered in LDS; loads for head h+1
// issued at start of head h, ds_write after PV (T14), 1 barrier per head.
__global__ __launch_bounds__(256, 1) void attn3(const unsigned short* __restrict__ tok,
                                                const unsigned short* __restrict__ M,
                                                const unsigned short* __restrict__ v,
                                                unsigned short* __restrict__ att) {
    __shared__ unsigned short Ms[2][80][328];   // 104,960 B (stride 328: 2-way free)
    __shared__ unsigned short Vt[2][48][104];   //  19,968 B
    __shared__ unsigned short Ps[128][104];     //  26,624 B  -> total 151,552 B

    int tid = threadIdx.x;
    int qt = blockIdx.x, b = blockIdx.y;
    int q0 = qt * 128;
    int lane = tid & 63, wv = tid >> 6;
    int fr = lane & 15, fg = lane >> 4;

    // ---- zero V pads (both buffers, fully) + Ps pad cols [80,104)
    {
        unsigned int* p = (unsigned int*)&Vt[0][0][0];
        for (int i = tid; i < 2 * 48 * 104 / 2; i += 256) p[i] = 0;
        for (int i = tid; i < 128 * 12; i += 256) {
            int r = i / 12, dw = i % 12;
            *(unsigned int*)&Ps[r][80 + dw * 2] = 0;
        }
    }

    // ---- tok fragments -> registers (live whole kernel)
    bf16x8_t atok[2][10];
    const size_t tokbase = ((size_t)b * S_ + q0) * 320;
    #pragma unroll
    for (int mf = 0; mf < 2; mf++)
        #pragma unroll
        for (int k = 0; k < 10; k++)
            atok[mf][k] = *(const bf16x8_t*)&tok[tokbase + (size_t)(wv * 32 + mf * 16 + fr) * 320 + k * 32 + fg * 8];

    const float scale = 0.15811388300841898f;  // 1/sqrt(40)

    // ---- prologue: stage head 0 into buffer 0
    {
        const size_t mb = (((size_t)b * 8 + 0) * 77) * 320;
        uint4 mreg[13], vreg[2];
        #pragma unroll
        for (int i = 0; i < 13; i++) {
            int idx = tid + i * 256;
            if (idx < 3200) {
                int r = idx / 40, c8 = (idx % 40) * 8;
                int rr = r < 77 ? r : 76;
                mreg[i] = *(const uint4*)&M[mb + (size_t)rr * 320 + c8];
            }
        }
        #pragma unroll
        for (int i = 0; i < 2; i++) {
            int idx = tid + i * 256;
            if (idx < 385) {
                int r = idx / 5, sg = idx % 5;
                vreg[i] = *(const uint4*)&v[((size_t)(b * LC + r)) * 320 + 0 * HD + sg * 8];
            }
        }
        __syncthreads();   // zeros done before stage writes
        #pragma unroll
        for (int i = 0; i < 13; i++) {
            int idx = tid + i * 256;
            if (idx < 3200) {
                int r = idx / 40, c8 = (idx % 40) * 8;
                *(uint4*)&Ms[0][r][c8] = mreg[i];
            }
        }
        #pragma unroll
        for (int i = 0; i < 2; i++) {
            int idx = tid + i * 256;
            if (idx < 385) {
                int r = idx / 5, sg = idx % 5;
                unsigned short e[8];
                *(uint4*)e = vreg[i];
                #pragma unroll
                for (int j = 0; j < 8; j++) Vt[0][sg * 8 + j][r] = e[j];
            }
        }
        __syncthreads();
    }

    for (int h = 0; h < 8; h++) {
        int cur = h & 1;

        // ---- issue next head's loads (T14: write to LDS after compute)
        uint4 mreg[13], vreg[2];
        if (h < 7) {
            const size_t mb = (((size_t)b * 8 + (h + 1)) * 77) * 320;
            #pragma unroll
            for (int i = 0; i < 13; i++) {
                int idx = tid + i * 256;
                if (idx < 3200) {
                    int r = idx / 40, c8 = (idx % 40) * 8;
                    int rr = r < 77 ? r : 76;
                    mreg[i] = *(const uint4*)&M[mb + (size_t)rr * 320 + c8];
                }
            }
            #pragma unroll
            for (int i = 0; i < 2; i++) {
                int idx = tid + i * 256;
                if (idx < 385) {
                    int r = idx / 5, sg = idx % 5;
                    vreg[i] = *(const uint4*)&v[((size_t)(b * LC + r)) * 320 + (h + 1) * HD + sg * 8];
                }
            }
        }

        // ---- scores: S = tok @ M_h^T  (K = 320, from registers x LDS)
        f32x4_t sc[2][5] = {};
        #pragma unroll
        for (int k = 0; k < 10; k++) {
            bf16x8_t bb[5];
            #pragma unroll
            for (int nf = 0; nf < 5; nf++)
                bb[nf] = *(const bf16x8_t*)&Ms[cur][nf * 16 + fr][k * 32 + fg * 8];
            #pragma unroll
            for (int mf = 0; mf < 2; mf++)
                #pragma unroll
                for (int nf = 0; nf < 5; nf++)
                    sc[mf][nf] = __builtin_amdgcn_mfma_f32_16x16x32_bf16(atok[mf][k], bb[nf], sc[mf][nf], 0, 0, 0);
        }

        // ---- masked softmax (rows mf*16+fg*4+r, cols nf*16+fr)
        float mx[2][4], sm[2][4];
        #pragma unroll
        for (int mf = 0; mf < 2; mf++)
            #pragma unroll
            for (int r = 0; r < 4; r++) {
                float m = -1e30f;
                #pragma unroll
                for (int nf = 0; nf < 5; nf++) {
                    float s = sc[mf][nf][r] * scale;
                    if (nf * 16 + fr >= LC) s = -1e30f;
                    sc[mf][nf][r] = s;
                    m = fmaxf(m, s);
                }
                mx[mf][r] = m;
            }
        #pragma unroll
        for (int off = 1; off < 16; off <<= 1)
            #pragma unroll
            for (int mf = 0; mf < 2; mf++)
                #pragma unroll
                for (int r = 0; r < 4; r++)
                    mx[mf][r] = fmaxf(mx[mf][r], __shfl_xor(mx[mf][r], off));
        #pragma unroll
        for (int mf = 0; mf < 2; mf++)
            #pragma unroll
            for (int r = 0; r < 4; r++) {
                float s = 0.f;
                #pragma unroll
                for (int nf = 0; nf < 5; nf++) {
                    float p = __expf(sc[mf][nf][r] - mx[mf][r]);
                    sc[mf][nf][r] = p;
                    s += p;
                }
                sm[mf][r] = s;
            }
        #pragma unroll
        for (int off = 1; off < 16; off <<= 1)
            #pragma unroll
            for (int mf = 0; mf < 2; mf++)
                #pragma unroll
                for (int r = 0; r < 4; r++)
                    sm[mf][r] += __shfl_xor(sm[mf][r], off);

        // ---- P -> LDS (wave-private rows; no barrier needed)
        #pragma unroll
        for (int mf = 0; mf < 2; mf++)
            #pragma unroll
            for (int nf = 0; nf < 5; nf++)
                #pragma unroll
                for (int r = 0; r < 4; r++)
                    Ps[wv * 32 + mf * 16 + fg * 4 + r][nf * 16 + fr] = f2bf(sc[mf][nf][r]);

        // ---- PV
        f32x4_t ov[2][3] = {};
        #pragma unroll
        for (int ks = 0; ks < 3; ks++) {
            bf16x8_t vb[3];
            #pragma unroll
            for (int nf = 0; nf < 3; nf++)
                vb[nf] = *(const bf16x8_t*)&Vt[cur][nf * 16 + fr][ks * 32 + fg * 8];
            #pragma unroll
            for (int mf = 0; mf < 2; mf++) {
                bf16x8_t pa = *(const bf16x8_t*)&Ps[wv * 32 + mf * 16 + fr][ks * 32 + fg * 8];
                #pragma unroll
                for (int nf = 0; nf < 3; nf++)
                    ov[mf][nf] = __builtin_amdgcn_mfma_f32_16x16x32_bf16(pa, vb[nf], ov[mf][nf], 0, 0, 0);
            }
        }

        // ---- normalize + store
        #pragma unroll
        for (int mf = 0; mf < 2; mf++) {
            float inv[4];
            #pragma unroll
            for (int r = 0; r < 4; r++) inv[r] = 1.f / sm[mf][r];
            #pragma unroll
            for (int nf = 0; nf < 3; nf++) {
                int d = nf * 16 + fr;
                if (d < HD) {
                    #pragma unroll
                    for (int r = 0; r < 4; r++) {
                        int qrow = q0 + wv * 32 + mf * 16 + fg * 4 + r;
                        att[((size_t)(b * S_ + qrow)) * 320 + h * HD + d] = f2bf(ov[mf][nf][r] * inv[r]);
                    }
                }
            }
        }

        // ---- write staged regs to the other buffer (vmcnt wait lands here)
        if (h < 7) {
            int nb = cur ^ 1;
            #pragma unroll
            for (int i = 0; i < 13; i++) {
                int idx = tid + i * 256;
                if (idx < 3200) {
                    int r = idx / 40, c8 = (idx % 40) * 8;
                    *(uint4*)&Ms[nb][r][c8] = mreg[i];
                }
            }
            #pragma unroll
            for (int i = 0; i < 2; i++) {
                int idx = tid + i * 256;
                if (idx < 385) {
                    int r = idx / 5, sg = idx % 5;
                    unsigned short e[8];
                    *(uint4*)e = vreg[i];
                    #pragma unroll
                    for (int j = 0; j < 8; j++) Vt[nb][sg * 8 + j][r] = e[j];
                }
            }
        }
        __syncthreads();
    }
}

// ---------------------------------------------------------------- GEMM core (64x64 tile, K=320)
__device__ __forceinline__ void gemm_core(const unsigned short* __restrict__ Ab,
                                          const unsigned short* __restrict__ Wb,
                                          unsigned short la[64][32],
                                          unsigned short lb[64][32],
                                          f32x4_t acc[2][2]) {
    int tid = threadIdx.x, lane = tid & 63, wid = tid >> 6;
    int wm = wid >> 1, wn = wid & 1;
    int lr = tid >> 2, lc = (tid & 3) * 8;
    int fr = lane & 15, kk = (lane >> 4) * 8;
    for (int k0 = 0; k0 < 320; k0 += 32) {
        *(uint4*)&la[lr][lc] = *(const uint4*)&Ab[(size_t)lr * 320 + k0 + lc];
        *(uint4*)&lb[lr][lc] = *(const uint4*)&Wb[(size_t)lr * 320 + k0 + lc];
        __syncthreads();
        bf16x8_t a0 = *(const bf16x8_t*)&la[wm * 32 + fr][kk];
        bf16x8_t a1 = *(const bf16x8_t*)&la[wm * 32 + 16 + fr][kk];
        bf16x8_t b0 = *(const bf16x8_t*)&lb[wn * 32 + fr][kk];
        bf16x8_t b1 = *(const bf16x8_t*)&lb[wn * 32 + 16 + fr][kk];
        acc[0][0] = __builtin_amdgcn_mfma_f32_16x16x32_bf16(a0, b0, acc[0][0], 0, 0, 0);
        acc[0][1] = __builtin_amdgcn_mfma_f32_16x16x32_bf16(a0, b1, acc[0][1], 0, 0, 0);
        acc[1][0] = __builtin_amdgcn_mfma_f32_16x16x32_bf16(a1, b0, acc[1][0], 0, 0, 0);
        acc[1][1] = __builtin_amdgcn_mfma_f32_16x16x32_bf16(a1, b1, acc[1][1], 0, 0, 0);
        __syncthreads();
    }
}

__global__ __launch_bounds__(256) void gemm_oproj(const unsigned short* __restrict__ A,
                                                  const unsigned short* __restrict__ W,
                                                  const float* __restrict__ bo,
                                                  const float* __restrict__ resid,
                                                  float* __restrict__ out) {
    __shared__ unsigned short la[64][32], lb[64][32];
    __shared__ float lt[64][65];
    int bm = blockIdx.x, bn = blockIdx.y, b = blockIdx.z;
    const unsigned short* Ab = A + ((size_t)b * S_ + bm * 64) * 320;
    const unsigned short* Wb = W + (size_t)bn * 64 * 320;
    f32x4_t acc[2][2] = {};
    gemm_core(Ab, Wb, la, lb, acc);
    int tid = threadIdx.x, lane = tid & 63, wid = tid >> 6;
    int wm = wid >> 1, wn = wid & 1;
    int fr = lane & 15, rg = (lane >> 4) * 4;
    #pragma unroll
    for (int mf = 0; mf < 2; mf++)
        #pragma unroll
        for (int nf = 0; nf < 2; nf++)
            #pragma unroll
            for (int r = 0; r < 4; r++)
                lt[wm * 32 + mf * 16 + rg + r][wn * 32 + nf * 16 + fr] = acc[mf][nf][r];
    __syncthreads();
    #pragma unroll
    for (int p = 0; p < 16; p++) {
        int nl = p * 4 + (tid >> 6);
        int sl = tid & 63;
        int n = bn * 64 + nl, s = bm * 64 + sl;
        size_t idx = ((size_t)b * 320 + n) * 4096 + s;
        out[idx] = lt[sl][nl] + bo[n] + resid[idx];
    }
}

// ---------------------------------------------------------------- launch
extern "C" void kernel_launch(void* const* d_in, const int* in_sizes, int n_in,
                              void* d_out, int out_size, void* d_ws, size_t ws_size,
                              hipStream_t stream) {
    const float* x    = (const float*)d_in[0];
    const float* ctx  = (const float*)d_in[1];
    const float* Wq   = (const float*)d_in[2];
    const float* Wk   = (const float*)d_in[3];
    const float* Wv   = (const float*)d_in[4];
    const float* Wo   = (const float*)d_in[5];
    const float* bo   = (const float*)d_in[6];
    const float* gns  = (const float*)d_in[7];
    const float* gnb  = (const float*)d_in[8];
    float* out = (float*)d_out;

    char* ws = (char*)d_ws;
    float2*         mr    = (float2*)(ws + 0);                  //     4,096
    unsigned short* wo_bf = (unsigned short*)(ws + 4096);       //   204,800 -> 208,896
    unsigned short* v_bf  = (unsigned short*)(ws + 208896);     //   788,480 -> 997,376
    unsigned short* Mbuf  = (unsigned short*)(ws + 997376);     // 6,307,840 -> 7,305,216
    unsigned short* tok   = (unsigned short*)(ws + 7305216);    // 41,943,040 -> 49,248,256
    unsigned short* att   = (unsigned short*)(ws + 49248256);   // 41,943,040 -> 91,191,296
    unsigned short* Ut    = att;                                // 3,932,160 (alias, disjoint lifetime)

    gn_stats<<<512, 256, 0, stream>>>(x, mr);
    castw<<<100, 256, 0, stream>>>(Wo, wo_bf);
    ukern<<<dim3(320, 8), 256, 0, stream>>>(Wk, Wq, Ut);
    kvM_gemm<<<dim3(20, 45), 256, 0, stream>>>(ctx, Wv, Ut, v_bf, Mbuf);
    norm_tr<<<dim3(128, 10, 16), 256, 0, stream>>>(x, mr, gns, gnb, tok);
    attn3<<<dim3(32, 16), 256, 0, stream>>>(tok, Mbuf, v_bf, att);
    gemm_oproj<<<dim3(64, 5, 16), 256, 0, stream>>>(att, wo_bf, bo, x, out);
}

// Round 6
// 209.884 us; speedup vs baseline: 1.3988x; 1.3988x over previous
//
#include <hip/hip_runtime.h>
#include <hip/hip_bf16.h>
#include <stdint.h>

#define B_    16
#define C_    320
#define S_    4096
#define G_    32
#define LC    77
#define CTX   768
#define HEADS 8
#define HD    40

typedef __bf16 bf16x8_t __attribute__((ext_vector_type(8)));
typedef float  f32x4_t  __attribute__((ext_vector_type(4)));

__device__ __forceinline__ unsigned short f2bf(float f) {
    union { float f; unsigned int u; } v; v.f = f;
    unsigned int r = v.u + 0x7fffu + ((v.u >> 16) & 1u);
    return (unsigned short)(r >> 16);
}
__device__ __forceinline__ float bf2f(unsigned short h) {
    union { unsigned int u; float f; } v; v.u = ((unsigned int)h) << 16;
    return v.f;
}

// async global->LDS, 16B per lane (dest = wave-uniform base + lane*16, linear)
__device__ __forceinline__ void gload16(const void* g, void* l) {
    __builtin_amdgcn_global_load_lds(
        (const __attribute__((address_space(1))) unsigned int*)g,
        (__attribute__((address_space(3))) unsigned int*)l, 16, 0, 0);
}

// ---------------------------------------------------------------- GN stats
__global__ __launch_bounds__(256) void gn_stats(const float* __restrict__ x,
                                                float2* __restrict__ mr) {
    int bg = blockIdx.x;
    const float4* p = (const float4*)(x + (size_t)bg * 40960);
    float s = 0.f, s2 = 0.f;
    for (int i = threadIdx.x; i < 10240; i += 256) {
        float4 v = p[i];
        s  += v.x + v.y + v.z + v.w;
        s2 += v.x * v.x + v.y * v.y + v.z * v.z + v.w * v.w;
    }
    for (int o = 32; o; o >>= 1) {
        s  += __shfl_down(s, o);
        s2 += __shfl_down(s2, o);
    }
    __shared__ float2 red[4];
    int lane = threadIdx.x & 63, wid = threadIdx.x >> 6;
    if (lane == 0) red[wid] = make_float2(s, s2);
    __syncthreads();
    if (threadIdx.x == 0) {
        float a = 0.f, c = 0.f;
        for (int i = 0; i < 4; i++) { a += red[i].x; c += red[i].y; }
        float mean = a / 40960.f;
        float var  = c / 40960.f - mean * mean;
        mr[bg] = make_float2(mean, rsqrtf(var + 1e-5f));
    }
}

// ---------------------------------------------------------------- weight cast
__global__ __launch_bounds__(256) void castw(const float* __restrict__ s,
                                             unsigned short* __restrict__ d) {
    int i = blockIdx.x * 256 + threadIdx.x;
    float4 v = ((const float4*)s)[i];
    ushort4 o;
    o.x = f2bf(v.x); o.y = f2bf(v.y); o.z = f2bf(v.z); o.w = f2bf(v.w);
    ((ushort4*)d)[i] = o;
}

// ---------------------------------------------------------------- normalize + transpose
__global__ __launch_bounds__(256) void norm_tr(const float* __restrict__ x,
                                               const float2* __restrict__ mr,
                                               const float* __restrict__ gns,
                                               const float* __restrict__ gnb,
                                               unsigned short* __restrict__ tok) {
    int s0 = blockIdx.x * 32, c0 = blockIdx.y * 32, b = blockIdx.z;
    __shared__ unsigned short t[32][33];
    int tx = threadIdx.x & 31, ty = threadIdx.x >> 5;
    #pragma unroll
    for (int i = 0; i < 4; i++) {
        int cl = i * 8 + ty;
        int c = c0 + cl;
        float2 m = mr[b * 32 + c / 10];
        float v = x[((size_t)(b * 320 + c)) * 4096 + s0 + tx];
        v = (v - m.x) * m.y * gns[c] + gnb[c];
        t[cl][tx] = f2bf(v);
    }
    __syncthreads();
    #pragma unroll
    for (int i = 0; i < 4; i++) {
        int sl = i * 8 + ty;
        tok[((size_t)b * 4096 + s0 + sl) * 320 + c0 + tx] = t[tx][sl];
    }
}

// ---------------------------------------------------------------- U kernel
__global__ __launch_bounds__(256) void ukern(const float* __restrict__ Wk,
                                             const float* __restrict__ Wq,
                                             unsigned short* __restrict__ Ut) {
    int c = blockIdx.x, h = blockIdx.y;
    int t = threadIdx.x;
    float a0 = 0.f, a1 = 0.f, a2 = 0.f;
    for (int d = 0; d < HD; d++) {
        float wq = Wq[(size_t)(h * HD + d) * 320 + c];
        const float* wkr = Wk + (size_t)(h * HD + d) * CTX;
        a0 += wq * wkr[t];
        a1 += wq * wkr[t + 256];
        a2 += wq * wkr[t + 512];
    }
    unsigned short* o = Ut + ((size_t)h * 320 + c) * CTX;
    o[t]       = f2bf(a0);
    o[t + 256] = f2bf(a1);
    o[t + 512] = f2bf(a2);
}

// ---------------------------------------------------------------- fused K/V/M projection GEMM
// cols 0..319: V = ctx @ Wv^T.  cols 320..2879: M_h = ctx @ Ut_h, written
// PRE-SWIZZLED into [80][320] tiles (idx16 ^= kv&7) for attn4's linear
// global_load_lds staging + conflict-free ds_read_b128.
__global__ __launch_bounds__(256) void kvM_gemm(const float* __restrict__ ctx,
                                                const float* __restrict__ Wv,
                                                const unsigned short* __restrict__ Ut,
                                                unsigned short* __restrict__ vout,
                                                unsigned short* __restrict__ Mout) {
    __shared__ unsigned short la[64][32], lb[64][32];
    int bm = blockIdx.x, bn = blockIdx.y;
    int tid = threadIdx.x, lane = tid & 63, wid = tid >> 6;
    int wm = wid >> 1, wn = wid & 1;
    int lr = tid >> 2, lc = (tid & 3) * 8;
    int fr = lane & 15, kk = (lane >> 4) * 8;

    int arow = bm * 64 + lr; if (arow > 1231) arow = 1231;
    const float* ap = ctx + (size_t)arow * CTX;
    bool isV = (bn < 5);
    const float* wp = isV ? (Wv + (size_t)(bn * 64 + lr) * CTX) : nullptr;
    const unsigned short* up = isV ? nullptr
        : (Ut + ((size_t)((bn - 5) / 5) * 320 + (size_t)((bn - 5) % 5) * 64 + lr) * CTX);

    f32x4_t acc[2][2] = {};
    for (int k0 = 0; k0 < CTX; k0 += 32) {
        float4 a4 = *(const float4*)&ap[k0 + lc];
        float4 a5 = *(const float4*)&ap[k0 + lc + 4];
        ushort4 pa0 = { f2bf(a4.x), f2bf(a4.y), f2bf(a4.z), f2bf(a4.w) };
        ushort4 pa1 = { f2bf(a5.x), f2bf(a5.y), f2bf(a5.z), f2bf(a5.w) };
        *(ushort4*)&la[lr][lc]     = pa0;
        *(ushort4*)&la[lr][lc + 4] = pa1;
        if (isV) {
            float4 w4 = *(const float4*)&wp[k0 + lc];
            float4 w5 = *(const float4*)&wp[k0 + lc + 4];
            ushort4 pw0 = { f2bf(w4.x), f2bf(w4.y), f2bf(w4.z), f2bf(w4.w) };
            ushort4 pw1 = { f2bf(w5.x), f2bf(w5.y), f2bf(w5.z), f2bf(w5.w) };
            *(ushort4*)&lb[lr][lc]     = pw0;
            *(ushort4*)&lb[lr][lc + 4] = pw1;
        } else {
            *(uint4*)&lb[lr][lc] = *(const uint4*)&up[k0 + lc];
        }
        __syncthreads();
        bf16x8_t a0 = *(const bf16x8_t*)&la[wm * 32 + fr][kk];
        bf16x8_t a1 = *(const bf16x8_t*)&la[wm * 32 + 16 + fr][kk];
        bf16x8_t b0 = *(const bf16x8_t*)&lb[wn * 32 + fr][kk];
        bf16x8_t b1 = *(const bf16x8_t*)&lb[wn * 32 + 16 + fr][kk];
        acc[0][0] = __builtin_amdgcn_mfma_f32_16x16x32_bf16(a0, b0, acc[0][0], 0, 0, 0);
        acc[0][1] = __builtin_amdgcn_mfma_f32_16x16x32_bf16(a0, b1, acc[0][1], 0, 0, 0);
        acc[1][0] = __builtin_amdgcn_mfma_f32_16x16x32_bf16(a1, b0, acc[1][0], 0, 0, 0);
        acc[1][1] = __builtin_amdgcn_mfma_f32_16x16x32_bf16(a1, b1, acc[1][1], 0, 0, 0);
        __syncthreads();
    }
    int rg = (lane >> 4) * 4;
    #pragma unroll
    for (int mf = 0; mf < 2; mf++)
        #pragma unroll
        for (int nf = 0; nf < 2; nf++)
            #pragma unroll
            for (int r = 0; r < 4; r++) {
                int row = bm * 64 + wm * 32 + mf * 16 + rg + r;
                if (row < 1232) {
                    int coloff = wn * 32 + nf * 16 + fr;
                    unsigned short val = f2bf(acc[mf][nf][r]);
                    if (isV) {
                        vout[(size_t)row * 320 + bn * 64 + coloff] = val;
                    } else {
                        int bb = row / 77, kv = row - bb * 77;
                        int hh = (bn - 5) / 5;
                        int c = ((bn - 5) % 5) * 64 + coloff;
                        size_t tile = ((size_t)bb * 8 + hh) * 25600;
                        int idx16 = kv * 40 + (c >> 3);
                        int swz = idx16 ^ (kv & 7);
                        Mout[tile + (size_t)swz * 8 + (c & 7)] = val;
                    }
                }
            }
}

// ---------------------------------------------------------------- fused attention v4
// block = (qt:128 rows, b); loop 8 heads. tok in regs (once). M_h staged via
// global_load_lds into swizzled 50KB LDS buffer; Ps aliases it after scores.
// Only vreg (8 VGPR) crosses barriers -> no spills. 60KB LDS -> 2 blocks/CU.
__global__ __launch_bounds__(256, 2) void attn4(const unsigned short* __restrict__ tok,
                                                const unsigned short* __restrict__ M,
                                                const unsigned short* __restrict__ v,
                                                unsigned short* __restrict__ att) {
    __shared__ unsigned short Msr[25600];        // 51,200 B swizzled M tile / Ps alias
    __shared__ unsigned short Vt[48][104];       //  9,984 B
    unsigned short (*Ps)[104] = (unsigned short (*)[104])Msr;

    int tid = threadIdx.x;
    int qt = blockIdx.x, b = blockIdx.y;
    int q0 = qt * 128;
    int lane = tid & 63, wv = tid >> 6;
    int fr = lane & 15, fg = lane >> 4;
    const float scale = 0.15811388300841898f;  // 1/sqrt(40)

    // zero Vt fully once (pads persist; live cells rewritten per head)
    {
        uint4 z = {0, 0, 0, 0};
        uint4* p = (uint4*)&Vt[0][0];
        for (int i = tid; i < 624; i += 256) p[i] = z;
    }

    // stage M tile h=0 (linear: source is pre-swizzled)
    {
        const unsigned short* Mt = M + ((size_t)b * 8 + 0) * 25600;
        #pragma unroll
        for (int i = 0; i < 13; i++) {
            int u = i * 256 + tid;
            if (u < 3200) gload16(Mt + (size_t)u * 8, &Msr[u * 8]);
        }
    }

    // V loads h=0
    uint4 vreg0, vreg1;
    {
        int r = tid / 5, sg = tid % 5;
        vreg0 = *(const uint4*)&v[((size_t)(b * LC + r)) * 320 + sg * 8];
        int idx = tid + 256;
        if (idx < 385) {
            r = idx / 5; sg = idx % 5;
            vreg1 = *(const uint4*)&v[((size_t)(b * LC + r)) * 320 + sg * 8];
        }
    }

    // tok fragments -> registers (whole kernel)
    bf16x8_t atok[2][10];
    const size_t tokbase = ((size_t)b * S_ + q0) * 320;
    #pragma unroll
    for (int mf = 0; mf < 2; mf++)
        #pragma unroll
        for (int k = 0; k < 10; k++)
            atok[mf][k] = *(const bf16x8_t*)&tok[tokbase + (size_t)(wv * 32 + mf * 16 + fr) * 320 + k * 32 + fg * 8];

    __syncthreads();  // zeros visible; stage h=0 drained (vmcnt0 at barrier); vregs arrived

    for (int h = 0; h < 8; h++) {
        // (a) write Vt for head h (prev-iter barrier guarantees prior PV done)
        {
            unsigned short e[8];
            int r = tid / 5, sg = tid % 5;
            *(uint4*)e = vreg0;
            #pragma unroll
            for (int j = 0; j < 8; j++) Vt[sg * 8 + j][r] = e[j];
            int idx = tid + 256;
            if (idx < 385) {
                r = idx / 5; sg = idx % 5;
                *(uint4*)e = vreg1;
                #pragma unroll
                for (int j = 0; j < 8; j++) Vt[sg * 8 + j][r] = e[j];
            }
        }
        // (b) issue V loads for h+1
        if (h < 7) {
            int r = tid / 5, sg = tid % 5;
            vreg0 = *(const uint4*)&v[((size_t)(b * LC + r)) * 320 + (h + 1) * HD + sg * 8];
            int idx = tid + 256;
            if (idx < 385) {
                r = idx / 5; sg = idx % 5;
                vreg1 = *(const uint4*)&v[((size_t)(b * LC + r)) * 320 + (h + 1) * HD + sg * 8];
            }
        }

        // (c) scores: S = tok @ M_h^T, K=320, regs x swizzled-LDS
        f32x4_t sc[2][5] = {};
        #pragma unroll
        for (int k = 0; k < 10; k++) {
            bf16x8_t bb[5];
            #pragma unroll
            for (int nf = 0; nf < 5; nf++) {
                int idx16 = (nf * 16 + fr) * 40 + k * 4 + fg;
                bb[nf] = *(const bf16x8_t*)&Msr[(size_t)(idx16 ^ (fr & 7)) * 8];
            }
            #pragma unroll
            for (int mf = 0; mf < 2; mf++)
                #pragma unroll
                for (int nf = 0; nf < 5; nf++)
                    sc[mf][nf] = __builtin_amdgcn_mfma_f32_16x16x32_bf16(atok[mf][k], bb[nf], sc[mf][nf], 0, 0, 0);
        }
        __syncthreads();  // (d) all waves done reading Msr

        // (e1) zero own-wave Ps pad cols [80,96)
        {
            uint4 z = {0, 0, 0, 0};
            int zr = wv * 32 + (lane >> 1);
            *(uint4*)((char*)&Ps[zr][80] + (lane & 1) * 16) = z;
        }

        // (e2) masked softmax (rows mf*16+fg*4+r, cols nf*16+fr)
        float mx[2][4], sm[2][4];
        #pragma unroll
        for (int mf = 0; mf < 2; mf++)
            #pragma unroll
            for (int r = 0; r < 4; r++) {
                float m = -1e30f;
                #pragma unroll
                for (int nf = 0; nf < 5; nf++) {
                    float s = sc[mf][nf][r] * scale;
                    if (nf * 16 + fr >= LC) s = -1e30f;
                    sc[mf][nf][r] = s;
                    m = fmaxf(m, s);
                }
                mx[mf][r] = m;
            }
        #pragma unroll
        for (int off = 1; off < 16; off <<= 1)
            #pragma unroll
            for (int mf = 0; mf < 2; mf++)
                #pragma unroll
                for (int r = 0; r < 4; r++)
                    mx[mf][r] = fmaxf(mx[mf][r], __shfl_xor(mx[mf][r], off));
        #pragma unroll
        for (int mf = 0; mf < 2; mf++)
            #pragma unroll
            for (int r = 0; r < 4; r++) {
                float s = 0.f;
                #pragma unroll
                for (int nf = 0; nf < 5; nf++) {
                    float p = __expf(sc[mf][nf][r] - mx[mf][r]);
                    sc[mf][nf][r] = p;
                    s += p;
                }
                sm[mf][r] = s;
            }
        #pragma unroll
        for (int off = 1; off < 16; off <<= 1)
            #pragma unroll
            for (int mf = 0; mf < 2; mf++)
                #pragma unroll
                for (int r = 0; r < 4; r++)
                    sm[mf][r] += __shfl_xor(sm[mf][r], off);

        // (e3) P -> LDS (wave-private rows)
        #pragma unroll
        for (int mf = 0; mf < 2; mf++)
            #pragma unroll
            for (int nf = 0; nf < 5; nf++)
                #pragma unroll
                for (int r = 0; r < 4; r++)
                    Ps[wv * 32 + mf * 16 + fg * 4 + r][nf * 16 + fr] = f2bf(sc[mf][nf][r]);

        // (e4) PV
        f32x4_t ov[2][3] = {};
        #pragma unroll
        for (int ks = 0; ks < 3; ks++) {
            bf16x8_t vb[3];
            #pragma unroll
            for (int nf = 0; nf < 3; nf++)
                vb[nf] = *(const bf16x8_t*)&Vt[nf * 16 + fr][ks * 32 + fg * 8];
            #pragma unroll
            for (int mf = 0; mf < 2; mf++) {
                bf16x8_t pa = *(const bf16x8_t*)&Ps[wv * 32 + mf * 16 + fr][ks * 32 + fg * 8];
                #pragma unroll
                for (int nf = 0; nf < 3; nf++)
                    ov[mf][nf] = __builtin_amdgcn_mfma_f32_16x16x32_bf16(pa, vb[nf], ov[mf][nf], 0, 0, 0);
            }
        }
        __syncthreads();  // (f) all waves done reading Ps/Vt

        // (g) stage M tile h+1 into Msr (overwrites Ps region - safe post-barrier)
        if (h < 7) {
            const unsigned short* Mn = M + ((size_t)b * 8 + h + 1) * 25600;
            #pragma unroll
            for (int i = 0; i < 13; i++) {
                int u = i * 256 + tid;
                if (u < 3200) gload16(Mn + (size_t)u * 8, &Msr[u * 8]);
            }
        }

        // (h) normalize + store att (overlaps stage latency)
        #pragma unroll
        for (int mf = 0; mf < 2; mf++) {
            float inv[4];
            #pragma unroll
            for (int r = 0; r < 4; r++) inv[r] = 1.f / sm[mf][r];
            #pragma unroll
            for (int nf = 0; nf < 3; nf++) {
                int d = nf * 16 + fr;
                if (d < HD) {
                    #pragma unroll
                    for (int r = 0; r < 4; r++) {
                        int qrow = q0 + wv * 32 + mf * 16 + fg * 4 + r;
                        att[((size_t)(b * S_ + qrow)) * 320 + h * HD + d] = f2bf(ov[mf][nf][r] * inv[r]);
                    }
                }
            }
        }
        __syncthreads();  // (i) drains stage vmcnt; orders next (a) after this PV
    }
}

// ---------------------------------------------------------------- GEMM core (64x64 tile, K=320)
__device__ __forceinline__ void gemm_core(const unsigned short* __restrict__ Ab,
                                          const unsigned short* __restrict__ Wb,
                                          unsigned short la[64][32],
                                          unsigned short lb[64][32],
                                          f32x4_t acc[2][2]) {
    int tid = threadIdx.x, lane = tid & 63, wid = tid >> 6;
    int wm = wid >> 1, wn = wid & 1;
    int lr = tid >> 2, lc = (tid & 3) * 8;
    int fr = lane & 15, kk = (lane >> 4) * 8;
    for (int k0 = 0; k0 < 320; k0 += 32) {
        *(uint4*)&la[lr][lc] = *(const uint4*)&Ab[(size_t)lr * 320 + k0 + lc];
        *(uint4*)&lb[lr][lc] = *(const uint4*)&Wb[(size_t)lr * 320 + k0 + lc];
        __syncthreads();
        bf16x8_t a0 = *(const bf16x8_t*)&la[wm * 32 + fr][kk];
        bf16x8_t a1 = *(const bf16x8_t*)&la[wm * 32 + 16 + fr][kk];
        bf16x8_t b0 = *(const bf16x8_t*)&lb[wn * 32 + fr][kk];
        bf16x8_t b1 = *(const bf16x8_t*)&lb[wn * 32 + 16 + fr][kk];
        acc[0][0] = __builtin_amdgcn_mfma_f32_16x16x32_bf16(a0, b0, acc[0][0], 0, 0, 0);
        acc[0][1] = __builtin_amdgcn_mfma_f32_16x16x32_bf16(a0, b1, acc[0][1], 0, 0, 0);
        acc[1][0] = __builtin_amdgcn_mfma_f32_16x16x32_bf16(a1, b0, acc[1][0], 0, 0, 0);
        acc[1][1] = __builtin_amdgcn_mfma_f32_16x16x32_bf16(a1, b1, acc[1][1], 0, 0, 0);
        __syncthreads();
    }
}

__global__ __launch_bounds__(256) void gemm_oproj(const unsigned short* __restrict__ A,
                                                  const unsigned short* __restrict__ W,
                                                  const float* __restrict__ bo,
                                                  const float* __restrict__ resid,
                                                  float* __restrict__ out) {
    __shared__ unsigned short la[64][32], lb[64][32];
    __shared__ float lt[64][65];
    int bm = blockIdx.x, bn = blockIdx.y, b = blockIdx.z;
    const unsigned short* Ab = A + ((size_t)b * S_ + bm * 64) * 320;
    const unsigned short* Wb = W + (size_t)bn * 64 * 320;
    f32x4_t acc[2][2] = {};
    gemm_core(Ab, Wb, la, lb, acc);
    int tid = threadIdx.x, lane = tid & 63, wid = tid >> 6;
    int wm = wid >> 1, wn = wid & 1;
    int fr = lane & 15, rg = (lane >> 4) * 4;
    #pragma unroll
    for (int mf = 0; mf < 2; mf++)
        #pragma unroll
        for (int nf = 0; nf < 2; nf++)
            #pragma unroll
            for (int r = 0; r < 4; r++)
                lt[wm * 32 + mf * 16 + rg + r][wn * 32 + nf * 16 + fr] = acc[mf][nf][r];
    __syncthreads();
    #pragma unroll
    for (int p = 0; p < 16; p++) {
        int nl = p * 4 + (tid >> 6);
        int sl = tid & 63;
        int n = bn * 64 + nl, s = bm * 64 + sl;
        size_t idx = ((size_t)b * 320 + n) * 4096 + s;
        out[idx] = lt[sl][nl] + bo[n] + resid[idx];
    }
}

// ---------------------------------------------------------------- launch
extern "C" void kernel_launch(void* const* d_in, const int* in_sizes, int n_in,
                              void* d_out, int out_size, void* d_ws, size_t ws_size,
                              hipStream_t stream) {
    const float* x    = (const float*)d_in[0];
    const float* ctx  = (const float*)d_in[1];
    const float* Wq   = (const float*)d_in[2];
    const float* Wk   = (const float*)d_in[3];
    const float* Wv   = (const float*)d_in[4];
    const float* Wo   = (const float*)d_in[5];
    const float* bo   = (const float*)d_in[6];
    const float* gns  = (const float*)d_in[7];
    const float* gnb  = (const float*)d_in[8];
    float* out = (float*)d_out;

    char* ws = (char*)d_ws;
    float2*         mr    = (float2*)(ws + 0);                 //      4,096
    unsigned short* wo_bf = (unsigned short*)(ws + 4096);      //    204,800 -> 208,896
    unsigned short* v_bf  = (unsigned short*)(ws + 208896);    //    788,480 -> 997,376
    unsigned short* Mbuf  = (unsigned short*)(ws + 997376);    //  6,553,600 -> 7,550,976 (16x8 tiles of 80x320)
    unsigned short* tok   = (unsigned short*)(ws + 7550976);   // 41,943,040 -> 49,494,016
    unsigned short* att   = (unsigned short*)(ws + 49494016);  // 41,943,040 -> 91,437,056
    unsigned short* Ut    = att;                               //  3,932,160 (alias, disjoint lifetime)

    gn_stats<<<512, 256, 0, stream>>>(x, mr);
    castw<<<100, 256, 0, stream>>>(Wo, wo_bf);
    ukern<<<dim3(320, 8), 256, 0, stream>>>(Wk, Wq, Ut);
    kvM_gemm<<<dim3(20, 45), 256, 0, stream>>>(ctx, Wv, Ut, v_bf, Mbuf);
    norm_tr<<<dim3(128, 10, 16), 256, 0, stream>>>(x, mr, gns, gnb, tok);
    attn4<<<dim3(32, 16), 256, 0, stream>>>(tok, Mbuf, v_bf, att);
    gemm_oproj<<<dim3(64, 5, 16), 256, 0, stream>>>(att, wo_bf, bo, x, out);
}

// Round 7
// 184.077 us; speedup vs baseline: 1.5949x; 1.1402x over previous
//
#include <hip/hip_runtime.h>
#include <hip/hip_bf16.h>
#include <stdint.h>

#define B_    16
#define C_    320
#define S_    4096
#define G_    32
#define LC    77
#define CTX   768
#define HEADS 8
#define HD    40

typedef __bf16 bf16x8_t __attribute__((ext_vector_type(8)));
typedef float  f32x4_t  __attribute__((ext_vector_type(4)));

__device__ __forceinline__ unsigned short f2bf(float f) {
    union { float f; unsigned int u; } v; v.f = f;
    unsigned int r = v.u + 0x7fffu + ((v.u >> 16) & 1u);
    return (unsigned short)(r >> 16);
}
__device__ __forceinline__ float bf2f(unsigned short h) {
    union { unsigned int u; float f; } v; v.u = ((unsigned int)h) << 16;
    return v.f;
}

// async global->LDS, 16B per lane (dest = wave-uniform base + lane*16, linear)
__device__ __forceinline__ void gload16(const void* g, void* l) {
    __builtin_amdgcn_global_load_lds(
        (const __attribute__((address_space(1))) unsigned int*)g,
        (__attribute__((address_space(3))) unsigned int*)l, 16, 0, 0);
}

// ---------------------------------------------------------------- GN stats
__global__ __launch_bounds__(256) void gn_stats(const float* __restrict__ x,
                                                float2* __restrict__ mr) {
    int bg = blockIdx.x;
    const float4* p = (const float4*)(x + (size_t)bg * 40960);
    float s = 0.f, s2 = 0.f;
    for (int i = threadIdx.x; i < 10240; i += 256) {
        float4 v = p[i];
        s  += v.x + v.y + v.z + v.w;
        s2 += v.x * v.x + v.y * v.y + v.z * v.z + v.w * v.w;
    }
    for (int o = 32; o; o >>= 1) {
        s  += __shfl_down(s, o);
        s2 += __shfl_down(s2, o);
    }
    __shared__ float2 red[4];
    int lane = threadIdx.x & 63, wid = threadIdx.x >> 6;
    if (lane == 0) red[wid] = make_float2(s, s2);
    __syncthreads();
    if (threadIdx.x == 0) {
        float a = 0.f, c = 0.f;
        for (int i = 0; i < 4; i++) { a += red[i].x; c += red[i].y; }
        float mean = a / 40960.f;
        float var  = c / 40960.f - mean * mean;
        mr[bg] = make_float2(mean, rsqrtf(var + 1e-5f));
    }
}

// ---------------------------------------------------------------- weight cast
__global__ __launch_bounds__(256) void castw(const float* __restrict__ s,
                                             unsigned short* __restrict__ d) {
    int i = blockIdx.x * 256 + threadIdx.x;
    float4 v = ((const float4*)s)[i];
    ushort4 o;
    o.x = f2bf(v.x); o.y = f2bf(v.y); o.z = f2bf(v.z); o.w = f2bf(v.w);
    ((ushort4*)d)[i] = o;
}

// ---------------------------------------------------------------- normalize + transpose
__global__ __launch_bounds__(256) void norm_tr(const float* __restrict__ x,
                                               const float2* __restrict__ mr,
                                               const float* __restrict__ gns,
                                               const float* __restrict__ gnb,
                                               unsigned short* __restrict__ tok) {
    int s0 = blockIdx.x * 32, c0 = blockIdx.y * 32, b = blockIdx.z;
    __shared__ unsigned short t[32][33];
    int tx = threadIdx.x & 31, ty = threadIdx.x >> 5;
    #pragma unroll
    for (int i = 0; i < 4; i++) {
        int cl = i * 8 + ty;
        int c = c0 + cl;
        float2 m = mr[b * 32 + c / 10];
        float v = x[((size_t)(b * 320 + c)) * 4096 + s0 + tx];
        v = (v - m.x) * m.y * gns[c] + gnb[c];
        t[cl][tx] = f2bf(v);
    }
    __syncthreads();
    #pragma unroll
    for (int i = 0; i < 4; i++) {
        int sl = i * 8 + ty;
        tok[((size_t)b * 4096 + s0 + sl) * 320 + c0 + tx] = t[tx][sl];
    }
}

// ---------------------------------------------------------------- U kernel
__global__ __launch_bounds__(256) void ukern(const float* __restrict__ Wk,
                                             const float* __restrict__ Wq,
                                             unsigned short* __restrict__ Ut) {
    int c = blockIdx.x, h = blockIdx.y;
    int t = threadIdx.x;
    float a0 = 0.f, a1 = 0.f, a2 = 0.f;
    for (int d = 0; d < HD; d++) {
        float wq = Wq[(size_t)(h * HD + d) * 320 + c];
        const float* wkr = Wk + (size_t)(h * HD + d) * CTX;
        a0 += wq * wkr[t];
        a1 += wq * wkr[t + 256];
        a2 += wq * wkr[t + 512];
    }
    unsigned short* o = Ut + ((size_t)h * 320 + c) * CTX;
    o[t]       = f2bf(a0);
    o[t + 256] = f2bf(a1);
    o[t + 512] = f2bf(a2);
}

// ---------------------------------------------------------------- fused K/V/M projection GEMM
// cols 0..319: V = ctx @ Wv^T.  cols 320..2879: M_h = ctx @ Ut_h, written
// PRE-SWIZZLED into [80][320] tiles (idx16 ^= kv&7) for attn4's linear
// global_load_lds staging + conflict-free ds_read_b128.
__global__ __launch_bounds__(256) void kvM_gemm(const float* __restrict__ ctx,
                                                const float* __restrict__ Wv,
                                                const unsigned short* __restrict__ Ut,
                                                unsigned short* __restrict__ vout,
                                                unsigned short* __restrict__ Mout) {
    __shared__ unsigned short la[64][32], lb[64][32];
    int bm = blockIdx.x, bn = blockIdx.y;
    int tid = threadIdx.x, lane = tid & 63, wid = tid >> 6;
    int wm = wid >> 1, wn = wid & 1;
    int lr = tid >> 2, lc = (tid & 3) * 8;
    int fr = lane & 15, kk = (lane >> 4) * 8;

    int arow = bm * 64 + lr; if (arow > 1231) arow = 1231;
    const float* ap = ctx + (size_t)arow * CTX;
    bool isV = (bn < 5);
    const float* wp = isV ? (Wv + (size_t)(bn * 64 + lr) * CTX) : nullptr;
    const unsigned short* up = isV ? nullptr
        : (Ut + ((size_t)((bn - 5) / 5) * 320 + (size_t)((bn - 5) % 5) * 64 + lr) * CTX);

    f32x4_t acc[2][2] = {};
    for (int k0 = 0; k0 < CTX; k0 += 32) {
        float4 a4 = *(const float4*)&ap[k0 + lc];
        float4 a5 = *(const float4*)&ap[k0 + lc + 4];
        ushort4 pa0 = { f2bf(a4.x), f2bf(a4.y), f2bf(a4.z), f2bf(a4.w) };
        ushort4 pa1 = { f2bf(a5.x), f2bf(a5.y), f2bf(a5.z), f2bf(a5.w) };
        *(ushort4*)&la[lr][lc]     = pa0;
        *(ushort4*)&la[lr][lc + 4] = pa1;
        if (isV) {
            float4 w4 = *(const float4*)&wp[k0 + lc];
            float4 w5 = *(const float4*)&wp[k0 + lc + 4];
            ushort4 pw0 = { f2bf(w4.x), f2bf(w4.y), f2bf(w4.z), f2bf(w4.w) };
            ushort4 pw1 = { f2bf(w5.x), f2bf(w5.y), f2bf(w5.z), f2bf(w5.w) };
            *(ushort4*)&lb[lr][lc]     = pw0;
            *(ushort4*)&lb[lr][lc + 4] = pw1;
        } else {
            *(uint4*)&lb[lr][lc] = *(const uint4*)&up[k0 + lc];
        }
        __syncthreads();
        bf16x8_t a0 = *(const bf16x8_t*)&la[wm * 32 + fr][kk];
        bf16x8_t a1 = *(const bf16x8_t*)&la[wm * 32 + 16 + fr][kk];
        bf16x8_t b0 = *(const bf16x8_t*)&lb[wn * 32 + fr][kk];
        bf16x8_t b1 = *(const bf16x8_t*)&lb[wn * 32 + 16 + fr][kk];
        acc[0][0] = __builtin_amdgcn_mfma_f32_16x16x32_bf16(a0, b0, acc[0][0], 0, 0, 0);
        acc[0][1] = __builtin_amdgcn_mfma_f32_16x16x32_bf16(a0, b1, acc[0][1], 0, 0, 0);
        acc[1][0] = __builtin_amdgcn_mfma_f32_16x16x32_bf16(a1, b0, acc[1][0], 0, 0, 0);
        acc[1][1] = __builtin_amdgcn_mfma_f32_16x16x32_bf16(a1, b1, acc[1][1], 0, 0, 0);
        __syncthreads();
    }
    int rg = (lane >> 4) * 4;
    #pragma unroll
    for (int mf = 0; mf < 2; mf++)
        #pragma unroll
        for (int nf = 0; nf < 2; nf++)
            #pragma unroll
            for (int r = 0; r < 4; r++) {
                int row = bm * 64 + wm * 32 + mf * 16 + rg + r;
                if (row < 1232) {
                    int coloff = wn * 32 + nf * 16 + fr;
                    unsigned short val = f2bf(acc[mf][nf][r]);
                    if (isV) {
                        vout[(size_t)row * 320 + bn * 64 + coloff] = val;
                    } else {
                        int bb = row / 77, kv = row - bb * 77;
                        int hh = (bn - 5) / 5;
                        int c = ((bn - 5) % 5) * 64 + coloff;
                        size_t tile = ((size_t)bb * 8 + hh) * 25600;
                        int idx16 = kv * 40 + (c >> 3);
                        int swz = idx16 ^ (kv & 7);
                        Mout[tile + (size_t)swz * 8 + (c & 7)] = val;
                    }
                }
            }
}

// ---------------------------------------------------------------- fused attention v4
__global__ __launch_bounds__(256, 2) void attn4(const unsigned short* __restrict__ tok,
                                                const unsigned short* __restrict__ M,
                                                const unsigned short* __restrict__ v,
                                                unsigned short* __restrict__ att) {
    __shared__ unsigned short Msr[25600];        // 51,200 B swizzled M tile / Ps alias
    __shared__ unsigned short Vt[48][104];       //  9,984 B
    unsigned short (*Ps)[104] = (unsigned short (*)[104])Msr;

    int tid = threadIdx.x;
    int qt = blockIdx.x, b = blockIdx.y;
    int q0 = qt * 128;
    int lane = tid & 63, wv = tid >> 6;
    int fr = lane & 15, fg = lane >> 4;
    const float scale = 0.15811388300841898f;  // 1/sqrt(40)

    // zero Vt fully once (pads persist; live cells rewritten per head)
    {
        uint4 z = {0, 0, 0, 0};
        uint4* p = (uint4*)&Vt[0][0];
        for (int i = tid; i < 624; i += 256) p[i] = z;
    }

    // stage M tile h=0 (linear: source is pre-swizzled)
    {
        const unsigned short* Mt = M + ((size_t)b * 8 + 0) * 25600;
        #pragma unroll
        for (int i = 0; i < 13; i++) {
            int u = i * 256 + tid;
            if (u < 3200) gload16(Mt + (size_t)u * 8, &Msr[u * 8]);
        }
    }

    // V loads h=0
    uint4 vreg0, vreg1;
    {
        int r = tid / 5, sg = tid % 5;
        vreg0 = *(const uint4*)&v[((size_t)(b * LC + r)) * 320 + sg * 8];
        int idx = tid + 256;
        if (idx < 385) {
            r = idx / 5; sg = idx % 5;
            vreg1 = *(const uint4*)&v[((size_t)(b * LC + r)) * 320 + sg * 8];
        }
    }

    // tok fragments -> registers (whole kernel)
    bf16x8_t atok[2][10];
    const size_t tokbase = ((size_t)b * S_ + q0) * 320;
    #pragma unroll
    for (int mf = 0; mf < 2; mf++)
        #pragma unroll
        for (int k = 0; k < 10; k++)
            atok[mf][k] = *(const bf16x8_t*)&tok[tokbase + (size_t)(wv * 32 + mf * 16 + fr) * 320 + k * 32 + fg * 8];

    __syncthreads();  // zeros visible; stage h=0 drained; vregs arrived

    for (int h = 0; h < 8; h++) {
        // (a) write Vt for head h
        {
            unsigned short e[8];
            int r = tid / 5, sg = tid % 5;
            *(uint4*)e = vreg0;
            #pragma unroll
            for (int j = 0; j < 8; j++) Vt[sg * 8 + j][r] = e[j];
            int idx = tid + 256;
            if (idx < 385) {
                r = idx / 5; sg = idx % 5;
                *(uint4*)e = vreg1;
                #pragma unroll
                for (int j = 0; j < 8; j++) Vt[sg * 8 + j][r] = e[j];
            }
        }
        // (b) issue V loads for h+1
        if (h < 7) {
            int r = tid / 5, sg = tid % 5;
            vreg0 = *(const uint4*)&v[((size_t)(b * LC + r)) * 320 + (h + 1) * HD + sg * 8];
            int idx = tid + 256;
            if (idx < 385) {
                r = idx / 5; sg = idx % 5;
                vreg1 = *(const uint4*)&v[((size_t)(b * LC + r)) * 320 + (h + 1) * HD + sg * 8];
            }
        }

        // (c) scores: S = tok @ M_h^T, K=320, regs x swizzled-LDS
        f32x4_t sc[2][5] = {};
        #pragma unroll
        for (int k = 0; k < 10; k++) {
            bf16x8_t bb[5];
            #pragma unroll
            for (int nf = 0; nf < 5; nf++) {
                int idx16 = (nf * 16 + fr) * 40 + k * 4 + fg;
                bb[nf] = *(const bf16x8_t*)&Msr[(size_t)(idx16 ^ (fr & 7)) * 8];
            }
            #pragma unroll
            for (int mf = 0; mf < 2; mf++)
                #pragma unroll
                for (int nf = 0; nf < 5; nf++)
                    sc[mf][nf] = __builtin_amdgcn_mfma_f32_16x16x32_bf16(atok[mf][k], bb[nf], sc[mf][nf], 0, 0, 0);
        }
        __syncthreads();  // (d) all waves done reading Msr

        // (e1) zero own-wave Ps pad cols [80,96)
        {
            uint4 z = {0, 0, 0, 0};
            int zr = wv * 32 + (lane >> 1);
            *(uint4*)((char*)&Ps[zr][80] + (lane & 1) * 16) = z;
        }

        // (e2) masked softmax (rows mf*16+fg*4+r, cols nf*16+fr)
        float mx[2][4], sm[2][4];
        #pragma unroll
        for (int mf = 0; mf < 2; mf++)
            #pragma unroll
            for (int r = 0; r < 4; r++) {
                float m = -1e30f;
                #pragma unroll
                for (int nf = 0; nf < 5; nf++) {
                    float s = sc[mf][nf][r] * scale;
                    if (nf * 16 + fr >= LC) s = -1e30f;
                    sc[mf][nf][r] = s;
                    m = fmaxf(m, s);
                }
                mx[mf][r] = m;
            }
        #pragma unroll
        for (int off = 1; off < 16; off <<= 1)
            #pragma unroll
            for (int mf = 0; mf < 2; mf++)
                #pragma unroll
                for (int r = 0; r < 4; r++)
                    mx[mf][r] = fmaxf(mx[mf][r], __shfl_xor(mx[mf][r], off));
        #pragma unroll
        for (int mf = 0; mf < 2; mf++)
            #pragma unroll
            for (int r = 0; r < 4; r++) {
                float s = 0.f;
                #pragma unroll
                for (int nf = 0; nf < 5; nf++) {
                    float p = __expf(sc[mf][nf][r] - mx[mf][r]);
                    sc[mf][nf][r] = p;
                    s += p;
                }
                sm[mf][r] = s;
            }
        #pragma unroll
        for (int off = 1; off < 16; off <<= 1)
            #pragma unroll
            for (int mf = 0; mf < 2; mf++)
                #pragma unroll
                for (int r = 0; r < 4; r++)
                    sm[mf][r] += __shfl_xor(sm[mf][r], off);

        // (e3) P -> LDS (wave-private rows)
        #pragma unroll
        for (int mf = 0; mf < 2; mf++)
            #pragma unroll
            for (int nf = 0; nf < 5; nf++)
                #pragma unroll
                for (int r = 0; r < 4; r++)
                    Ps[wv * 32 + mf * 16 + fg * 4 + r][nf * 16 + fr] = f2bf(sc[mf][nf][r]);

        // (e4) PV
        f32x4_t ov[2][3] = {};
        #pragma unroll
        for (int ks = 0; ks < 3; ks++) {
            bf16x8_t vb[3];
            #pragma unroll
            for (int nf = 0; nf < 3; nf++)
                vb[nf] = *(const bf16x8_t*)&Vt[nf * 16 + fr][ks * 32 + fg * 8];
            #pragma unroll
            for (int mf = 0; mf < 2; mf++) {
                bf16x8_t pa = *(const bf16x8_t*)&Ps[wv * 32 + mf * 16 + fr][ks * 32 + fg * 8];
                #pragma unroll
                for (int nf = 0; nf < 3; nf++)
                    ov[mf][nf] = __builtin_amdgcn_mfma_f32_16x16x32_bf16(pa, vb[nf], ov[mf][nf], 0, 0, 0);
            }
        }
        __syncthreads();  // (f) all waves done reading Ps/Vt

        // (g) stage M tile h+1
        if (h < 7) {
            const unsigned short* Mn = M + ((size_t)b * 8 + h + 1) * 25600;
            #pragma unroll
            for (int i = 0; i < 13; i++) {
                int u = i * 256 + tid;
                if (u < 3200) gload16(Mn + (size_t)u * 8, &Msr[u * 8]);
            }
        }

        // (h) normalize + store att
        #pragma unroll
        for (int mf = 0; mf < 2; mf++) {
            float inv[4];
            #pragma unroll
            for (int r = 0; r < 4; r++) inv[r] = 1.f / sm[mf][r];
            #pragma unroll
            for (int nf = 0; nf < 3; nf++) {
                int d = nf * 16 + fr;
                if (d < HD) {
                    #pragma unroll
                    for (int r = 0; r < 4; r++) {
                        int qrow = q0 + wv * 32 + mf * 16 + fg * 4 + r;
                        att[((size_t)(b * S_ + qrow)) * 320 + h * HD + d] = f2bf(ov[mf][nf][r] * inv[r]);
                    }
                }
            }
        }
        __syncthreads();  // (i) drains stage vmcnt; orders next (a) after this PV
    }
}

// ---------------------------------------------------------------- output projection v2
// out[b][n][s] = sum_e att[b][s][e] * Wo[n][e] + bo[n] + resid[b][n][s]
// Block: 64 s-rows x ALL 320 n. A = Wo (n rows), B = att (s rows);
// C[n][s]: n = wv*80 + nf*16 + fg*4 + r, s = s0 + sf*16 + fr (64B coalesced).
// LDS rows padded 64B->80B: 16B-slot stride 5 coprime 8 -> conflict-free.
__global__ __launch_bounds__(256) void gemm_oproj2(const unsigned short* __restrict__ att,
                                                   const unsigned short* __restrict__ wo,
                                                   const float* __restrict__ bo,
                                                   const float* __restrict__ resid,
                                                   float* __restrict__ out) {
    __shared__ unsigned short lw[320 * 40];  // Wo K-slice, 25.6 KB
    __shared__ unsigned short la[64 * 40];   // att K-slice, 5.1 KB
    int tid = threadIdx.x, lane = tid & 63, wv = tid >> 6;
    int fr = lane & 15, fg = lane >> 4;
    int bm = blockIdx.x, b = blockIdx.y;
    int s0 = bm * 64;
    const size_t abase = ((size_t)b * S_ + s0) * 320;

    f32x4_t acc[5][4] = {};  // [n-frag][s-frag]

    for (int k0 = 0; k0 < 320; k0 += 32) {
        #pragma unroll
        for (int i = 0; i < 7; i++) {
            int u = i * 256 + tid;
            if (u < 1600) {
                int row = u / 5, ch = u % 5;
                int c = ch < 4 ? ch : 0;  // pad chunk: points at row start, never read
                gload16(wo + (size_t)row * 320 + k0 + c * 8, &lw[(size_t)u * 8]);
            }
        }
        {
            int u = tid;
            int row = u / 5, ch = u % 5;
            int c = ch < 4 ? ch : 0;
            gload16(att + abase + (size_t)row * 320 + k0 + c * 8, &la[(size_t)u * 8]);
            u = tid + 256;
            if (u < 320) {
                row = u / 5; ch = u % 5; c = ch < 4 ? ch : 0;
                gload16(att + abase + (size_t)row * 320 + k0 + c * 8, &la[(size_t)u * 8]);
            }
        }
        __syncthreads();  // drains vmcnt -> LDS ready
        bf16x8_t bfrag[4];
        #pragma unroll
        for (int sf = 0; sf < 4; sf++)
            bfrag[sf] = *(const bf16x8_t*)&la[(sf * 16 + fr) * 40 + fg * 8];
        #pragma unroll
        for (int nf = 0; nf < 5; nf++) {
            bf16x8_t afrag = *(const bf16x8_t*)&lw[(wv * 80 + nf * 16 + fr) * 40 + fg * 8];
            #pragma unroll
            for (int sf = 0; sf < 4; sf++)
                acc[nf][sf] = __builtin_amdgcn_mfma_f32_16x16x32_bf16(afrag, bfrag[sf], acc[nf][sf], 0, 0, 0);
        }
        __syncthreads();  // all reads done before next stage overwrites
    }

    // epilogue: direct coalesced stores (64B per quarter-wave), bias + residual
    int nbase = wv * 80;
    #pragma unroll
    for (int nf = 0; nf < 5; nf++) {
        #pragma unroll
        for (int r = 0; r < 4; r++) {
            int n = nbase + nf * 16 + fg * 4 + r;
            float bov = bo[n];
            size_t rowb = ((size_t)(b * 320 + n)) * 4096 + s0;
            #pragma unroll
            for (int sf = 0; sf < 4; sf++) {
                int s = sf * 16 + fr;
                out[rowb + s] = acc[nf][sf][r] + bov + resid[rowb + s];
            }
        }
    }
}

// ---------------------------------------------------------------- launch
extern "C" void kernel_launch(void* const* d_in, const int* in_sizes, int n_in,
                              void* d_out, int out_size, void* d_ws, size_t ws_size,
                              hipStream_t stream) {
    const float* x    = (const float*)d_in[0];
    const float* ctx  = (const float*)d_in[1];
    const float* Wq   = (const float*)d_in[2];
    const float* Wk   = (const float*)d_in[3];
    const float* Wv   = (const float*)d_in[4];
    const float* Wo   = (const float*)d_in[5];
    const float* bo   = (const float*)d_in[6];
    const float* gns  = (const float*)d_in[7];
    const float* gnb  = (const float*)d_in[8];
    float* out = (float*)d_out;

    char* ws = (char*)d_ws;
    float2*         mr    = (float2*)(ws + 0);                 //      4,096
    unsigned short* wo_bf = (unsigned short*)(ws + 4096);      //    204,800 -> 208,896
    unsigned short* v_bf  = (unsigned short*)(ws + 208896);    //    788,480 -> 997,376
    unsigned short* Mbuf  = (unsigned short*)(ws + 997376);    //  6,553,600 -> 7,550,976
    unsigned short* tok   = (unsigned short*)(ws + 7550976);   // 41,943,040 -> 49,494,016
    unsigned short* att   = (unsigned short*)(ws + 49494016);  // 41,943,040 -> 91,437,056
    unsigned short* Ut    = att;                               //  3,932,160 (alias, disjoint lifetime)

    gn_stats<<<512, 256, 0, stream>>>(x, mr);
    castw<<<100, 256, 0, stream>>>(Wo, wo_bf);
    ukern<<<dim3(320, 8), 256, 0, stream>>>(Wk, Wq, Ut);
    kvM_gemm<<<dim3(20, 45), 256, 0, stream>>>(ctx, Wv, Ut, v_bf, Mbuf);
    norm_tr<<<dim3(128, 10, 16), 256, 0, stream>>>(x, mr, gns, gnb, tok);
    attn4<<<dim3(32, 16), 256, 0, stream>>>(tok, Mbuf, v_bf, att);
    gemm_oproj2<<<dim3(64, 16), 256, 0, stream>>>(att, wo_bf, bo, x, out);
}